// Round 1
// baseline (196.733 us; speedup 1.0000x reference)
//
#include <hip/hip_runtime.h>
#include <hip/hip_bf16.h>

// GATConv: N=50000, E=1.6M (row sorted), IN_C=128, HEADS=4, OUT_C=32 (H*C=128)
// Pipeline:
//   1) gemm_kernel:   xp = x @ W            [N,128] fp32 vector GEMM
//   2) att_kernel:    a_src/a_dst = <xp, att_src/att_dst> per (n,h)
//   3) rowptr_kernel: CSR offsets via binary search over sorted `row`
//   4) agg_kernel:    per-node softmax over incident edges + weighted gather of xp[col]

#define IN_C 128
#define HC 128   // HEADS*OUT_C
#define GR 32    // rows per GEMM block

__global__ __launch_bounds__(256) void gemm_kernel(const float* __restrict__ x,
                                                   const float* __restrict__ W,
                                                   float* __restrict__ xp, int n_nodes) {
    __shared__ float xs[GR * IN_C];
    const int base = blockIdx.x * GR;
    const int tid = threadIdx.x;

    // stage x tile (32 rows x 128 f32 = 16 KB) coalesced as float4
    #pragma unroll
    for (int j = 0; j < 4; ++j) {
        int idx = tid + j * 256;              // float4 index within tile, 1024 total
        int r = base + (idx >> 5);            // 32 float4 per row
        float4 v = make_float4(0.f, 0.f, 0.f, 0.f);
        if (r < n_nodes)
            v = *(const float4*)(x + (size_t)base * IN_C + (size_t)idx * 4);
        *(float4*)(xs + idx * 4) = v;
    }
    __syncthreads();

    const int wid = tid >> 6, lane = tid & 63;
    float acc[8][2] = {};
    const float* wp = W + 2 * lane;
    for (int k = 0; k < IN_C; ++k) {
        float2 wv = *(const float2*)(wp + (size_t)k * HC);
        #pragma unroll
        for (int r = 0; r < 8; ++r) {
            float xv = xs[(wid * 8 + r) * IN_C + k];
            acc[r][0] = fmaf(xv, wv.x, acc[r][0]);
            acc[r][1] = fmaf(xv, wv.y, acc[r][1]);
        }
    }
    #pragma unroll
    for (int r = 0; r < 8; ++r) {
        int gr = base + wid * 8 + r;
        if (gr < n_nodes)
            *(float2*)(xp + (size_t)gr * HC + 2 * lane) = make_float2(acc[r][0], acc[r][1]);
    }
}

__global__ __launch_bounds__(256) void att_kernel(const float* __restrict__ xp,
                                                  const float* __restrict__ att_src,
                                                  const float* __restrict__ att_dst,
                                                  float* __restrict__ a_src,
                                                  float* __restrict__ a_dst, int n_nodes) {
    const int wid = threadIdx.x >> 6, lane = threadIdx.x & 63;
    const int n = blockIdx.x * 4 + wid;
    if (n >= n_nodes) return;
    float2 xv = *(const float2*)(xp + (size_t)n * HC + 2 * lane);
    float2 ws = *(const float2*)(att_src + 2 * lane);
    float2 wd = *(const float2*)(att_dst + 2 * lane);
    float ps = xv.x * ws.x + xv.y * ws.y;
    float pd = xv.x * wd.x + xv.y * wd.y;
    #pragma unroll
    for (int off = 1; off < 16; off <<= 1) {
        ps += __shfl_xor(ps, off, 64);
        pd += __shfl_xor(pd, off, 64);
    }
    if ((lane & 15) == 0) {
        int h = lane >> 4;
        a_src[n * 4 + h] = ps;
        a_dst[n * 4 + h] = pd;
    }
}

__global__ __launch_bounds__(256) void rowptr_kernel(const int* __restrict__ row,
                                                     int* __restrict__ row_ptr,
                                                     int n_nodes, int E) {
    int n = blockIdx.x * blockDim.x + threadIdx.x;
    if (n > n_nodes) return;
    int lo = 0, hi = E;
    while (lo < hi) {
        int mid = (lo + hi) >> 1;
        if (row[mid] < n) lo = mid + 1; else hi = mid;
    }
    row_ptr[n] = lo;
}

__global__ __launch_bounds__(128) void agg_kernel(const float* __restrict__ xp,
                                                  const float* __restrict__ a_src,
                                                  const float* __restrict__ a_dst,
                                                  const int* __restrict__ col,
                                                  const int* __restrict__ row_ptr,
                                                  const float* __restrict__ bias,
                                                  float* __restrict__ out, int n_nodes) {
    const int n = blockIdx.x;
    const int start = row_ptr[n], end = row_ptr[n + 1];
    const int tid = threadIdx.x;
    const int lane = tid & 63, wid = tid >> 6;
    const int hh = tid & 3;

    __shared__ float red_m[2][4], red_s[2][4];

    const float as_h = a_src[n * 4 + hh];

    // phase 1: per-head max over segment (clamped at 0 to match max(0, seg_max))
    float m_local = 0.0f;
    for (int e = start + (tid >> 2); e < end; e += 32) {
        int c64 = col[e];
        float v = as_h + a_dst[c64 * 4 + hh];
        v = v > 0.0f ? v : 0.2f * v;
        m_local = fmaxf(m_local, v);
    }
    #pragma unroll
    for (int off = 4; off < 64; off <<= 1)
        m_local = fmaxf(m_local, __shfl_xor(m_local, off, 64));
    if (lane < 4) red_m[wid][lane] = m_local;
    __syncthreads();
    const float mh = fmaxf(red_m[0][hh], red_m[1][hh]);

    // phase 2: per-head sum of exp
    float s_local = 0.0f;
    for (int e = start + (tid >> 2); e < end; e += 32) {
        int c64 = col[e];
        float v = as_h + a_dst[c64 * 4 + hh];
        v = v > 0.0f ? v : 0.2f * v;
        s_local += __expf(v - mh);
    }
    #pragma unroll
    for (int off = 4; off < 64; off <<= 1)
        s_local += __shfl_xor(s_local, off, 64);
    if (lane < 4) red_s[wid][lane] = s_local;
    __syncthreads();

    // phase 3: weighted accumulate; thread owns output channel `tid`
    const int h4 = tid >> 5;
    const float m4 = fmaxf(red_m[0][h4], red_m[1][h4]);
    const float s4 = red_s[0][h4] + red_s[1][h4];
    const float inv = 1.0f / (s4 + 1e-8f);
    const float as4 = a_src[n * 4 + h4];

    float acc = 0.0f;
    int e = start;
    for (; e + 1 < end; e += 2) {
        int c0 = col[e], c1 = col[e + 1];
        float v0 = as4 + a_dst[c0 * 4 + h4];
        float v1 = as4 + a_dst[c1 * 4 + h4];
        v0 = v0 > 0.0f ? v0 : 0.2f * v0;
        v1 = v1 > 0.0f ? v1 : 0.2f * v1;
        float w0 = __expf(v0 - m4) * inv;
        float w1 = __expf(v1 - m4) * inv;
        float x0 = xp[(size_t)c0 * HC + tid];
        float x1 = xp[(size_t)c1 * HC + tid];
        acc = fmaf(w0, x0, acc);
        acc = fmaf(w1, x1, acc);
    }
    if (e < end) {
        int c0 = col[e];
        float v0 = as4 + a_dst[c0 * 4 + h4];
        v0 = v0 > 0.0f ? v0 : 0.2f * v0;
        acc = fmaf(__expf(v0 - m4) * inv, xp[(size_t)c0 * HC + tid], acc);
    }
    out[(size_t)n * HC + tid] = acc + bias[tid];
}

extern "C" void kernel_launch(void* const* d_in, const int* in_sizes, int n_in,
                              void* d_out, int out_size, void* d_ws, size_t ws_size,
                              hipStream_t stream) {
    const float* x       = (const float*)d_in[0];
    const float* weight  = (const float*)d_in[1];
    const float* att_src = (const float*)d_in[2];
    const float* att_dst = (const float*)d_in[3];
    const float* bias    = (const float*)d_in[4];
    const int*   row     = (const int*)d_in[5];
    const int*   col     = (const int*)d_in[6];
    float* out = (float*)d_out;

    const int n_nodes = in_sizes[0] / IN_C;   // 50000
    const int E = in_sizes[5];                // 1.6M

    // workspace layout
    char* ws = (char*)d_ws;
    float* xp     = (float*)ws;                         ws += (size_t)n_nodes * HC * sizeof(float);
    float* a_src  = (float*)ws;                         ws += (size_t)n_nodes * 4 * sizeof(float);
    float* a_dst  = (float*)ws;                         ws += (size_t)n_nodes * 4 * sizeof(float);
    int*   row_ptr = (int*)ws;                          ws += (size_t)(n_nodes + 1) * sizeof(int);

    gemm_kernel<<<(n_nodes + GR - 1) / GR, 256, 0, stream>>>(x, weight, xp, n_nodes);
    att_kernel<<<(n_nodes + 3) / 4, 256, 0, stream>>>(xp, att_src, att_dst, a_src, a_dst, n_nodes);
    rowptr_kernel<<<(n_nodes + 256) / 256, 256, 0, stream>>>(row, row_ptr, n_nodes, E);
    agg_kernel<<<n_nodes, 128, 0, stream>>>(xp, a_src, a_dst, col, row_ptr, bias, out, n_nodes);
}

// Round 2
// 106.749 us; speedup vs baseline: 1.8429x; 1.8429x over previous
//
#include <hip/hip_runtime.h>
#include <hip/hip_bf16.h>

// GATConv: N=50000, E=1.6M (row sorted), IN_C=128, HEADS=4, OUT_C=32 (H*C=128)
//   1) gemm_kernel:   xp(bf16 packed) = x @ W, fused a_src/a_dst epilogue
//   2) rowptr_kernel: CSR offsets via binary search over sorted `row`
//   3) agg_kernel:    per-node (1 wave/node) softmax + bf16 gather-accumulate

#define IN_C 128
#define HC 128   // HEADS*OUT_C
#define GR 32    // rows per GEMM block
#define STG 256  // staged edges per node (deg>STG falls back to recompute path)

static __device__ inline unsigned short f2bf(float f) {
    unsigned u = __float_as_uint(f);
    unsigned r = (u + 0x7fffu + ((u >> 16) & 1u)) >> 16;  // round-nearest-even
    return (unsigned short)r;
}

__global__ __launch_bounds__(256) void gemm_kernel(const float* __restrict__ x,
                                                   const float* __restrict__ W,
                                                   const float* __restrict__ att_src_w,
                                                   const float* __restrict__ att_dst_w,
                                                   unsigned* __restrict__ xp,
                                                   float* __restrict__ a_src,
                                                   float* __restrict__ a_dst, int n_nodes) {
    __shared__ float xs[GR * IN_C];
    const int base = blockIdx.x * GR;
    const int tid = threadIdx.x;

    #pragma unroll
    for (int j = 0; j < 4; ++j) {
        int idx = tid + j * 256;              // float4 index within tile
        int r = base + (idx >> 5);            // 32 float4 per row
        float4 v = make_float4(0.f, 0.f, 0.f, 0.f);
        if (r < n_nodes)
            v = *(const float4*)(x + (size_t)base * IN_C + (size_t)idx * 4);
        *(float4*)(xs + idx * 4) = v;
    }
    __syncthreads();

    const int wid = tid >> 6, lane = tid & 63;
    float acc[8][2] = {};
    const float* wp = W + 2 * lane;
    for (int k = 0; k < IN_C; ++k) {
        float2 wv = *(const float2*)(wp + (size_t)k * HC);
        #pragma unroll
        for (int r = 0; r < 8; ++r) {
            float xv = xs[(wid * 8 + r) * IN_C + k];
            acc[r][0] = fmaf(xv, wv.x, acc[r][0]);
            acc[r][1] = fmaf(xv, wv.y, acc[r][1]);
        }
    }

    // fused attention-logit epilogue + bf16 store
    float2 aw_s = *(const float2*)(att_src_w + 2 * lane);
    float2 aw_d = *(const float2*)(att_dst_w + 2 * lane);
    const int h = lane >> 4;   // lanes 16h..16h+15 own head h's 32 channels
    #pragma unroll
    for (int r = 0; r < 8; ++r) {
        int gr = base + wid * 8 + r;
        float ps = acc[r][0] * aw_s.x + acc[r][1] * aw_s.y;
        float pd = acc[r][0] * aw_d.x + acc[r][1] * aw_d.y;
        #pragma unroll
        for (int off = 1; off < 16; off <<= 1) {
            ps += __shfl_xor(ps, off, 16);
            pd += __shfl_xor(pd, off, 16);
        }
        if (gr < n_nodes) {
            unsigned packed = (unsigned)f2bf(acc[r][0]) | ((unsigned)f2bf(acc[r][1]) << 16);
            xp[(size_t)gr * 64 + lane] = packed;
            if ((lane & 15) == 0) {
                a_src[(size_t)gr * 4 + h] = ps;
                a_dst[(size_t)gr * 4 + h] = pd;
            }
        }
    }
}

__global__ __launch_bounds__(256) void rowptr_kernel(const int* __restrict__ row,
                                                     int* __restrict__ row_ptr,
                                                     int n_nodes, int E) {
    int n = blockIdx.x * blockDim.x + threadIdx.x;
    if (n > n_nodes) return;
    int lo = 0, hi = E;
    while (lo < hi) {
        int mid = (lo + hi) >> 1;
        if (row[mid] < n) lo = mid + 1; else hi = mid;
    }
    row_ptr[n] = lo;
}

// One wave per node; lane owns channels (2*lane, 2*lane+1), head h = lane>>4.
__global__ __launch_bounds__(128) void agg_kernel(const unsigned* __restrict__ xp,
                                                  const float* __restrict__ a_src,
                                                  const float* __restrict__ a_dst,
                                                  const int* __restrict__ col,
                                                  const int* __restrict__ row_ptr,
                                                  const float* __restrict__ bias,
                                                  float* __restrict__ out, int n_nodes) {
    __shared__ float lds_w[2][STG * 4];   // per-wave: logits -> weights
    __shared__ int   lds_c[2][STG];
    const int wid = threadIdx.x >> 6, lane = threadIdx.x & 63;
    const int n = blockIdx.x * 2 + wid;
    const bool alive = n < n_nodes;

    int start = 0, deg = 0;
    if (alive) { start = row_ptr[n]; deg = row_ptr[n + 1] - start; }
    const bool staged = deg <= STG;
    float4 as4 = alive ? *(const float4*)(a_src + (size_t)n * 4)
                       : make_float4(0.f, 0.f, 0.f, 0.f);

    // Phase A: logits -> LDS, track per-head max (clamped at 0: max(0, seg_max))
    float m0 = 0.f, m1 = 0.f, m2 = 0.f, m3 = 0.f;
    if (staged) {
        for (int i = lane; i < deg; i += 64) {
            int c = col[start + i];
            float4 ad = *(const float4*)(a_dst + (size_t)c * 4);
            float v0 = as4.x + ad.x, v1 = as4.y + ad.y, v2 = as4.z + ad.z, v3 = as4.w + ad.w;
            v0 = v0 > 0.f ? v0 : 0.2f * v0;  v1 = v1 > 0.f ? v1 : 0.2f * v1;
            v2 = v2 > 0.f ? v2 : 0.2f * v2;  v3 = v3 > 0.f ? v3 : 0.2f * v3;
            lds_c[wid][i] = c;
            *(float4*)&lds_w[wid][i * 4] = make_float4(v0, v1, v2, v3);
            m0 = fmaxf(m0, v0); m1 = fmaxf(m1, v1); m2 = fmaxf(m2, v2); m3 = fmaxf(m3, v3);
        }
    } else {
        for (int i = lane; i < deg; i += 64) {
            int c = col[start + i];
            float4 ad = *(const float4*)(a_dst + (size_t)c * 4);
            float v0 = as4.x + ad.x, v1 = as4.y + ad.y, v2 = as4.z + ad.z, v3 = as4.w + ad.w;
            v0 = v0 > 0.f ? v0 : 0.2f * v0;  v1 = v1 > 0.f ? v1 : 0.2f * v1;
            v2 = v2 > 0.f ? v2 : 0.2f * v2;  v3 = v3 > 0.f ? v3 : 0.2f * v3;
            m0 = fmaxf(m0, v0); m1 = fmaxf(m1, v1); m2 = fmaxf(m2, v2); m3 = fmaxf(m3, v3);
        }
    }
    #pragma unroll
    for (int off = 1; off < 64; off <<= 1) {
        m0 = fmaxf(m0, __shfl_xor(m0, off, 64));
        m1 = fmaxf(m1, __shfl_xor(m1, off, 64));
        m2 = fmaxf(m2, __shfl_xor(m2, off, 64));
        m3 = fmaxf(m3, __shfl_xor(m3, off, 64));
    }

    // Phase B: weights (unnormalized) in-place, per-head sum
    float s0 = 0.f, s1 = 0.f, s2 = 0.f, s3 = 0.f;
    if (staged) {
        for (int i = lane; i < deg; i += 64) {          // same lane wrote these slots
            float4 v = *(float4*)&lds_w[wid][i * 4];
            float w0 = __expf(v.x - m0), w1 = __expf(v.y - m1);
            float w2 = __expf(v.z - m2), w3 = __expf(v.w - m3);
            *(float4*)&lds_w[wid][i * 4] = make_float4(w0, w1, w2, w3);
            s0 += w0; s1 += w1; s2 += w2; s3 += w3;
        }
    } else {
        for (int i = lane; i < deg; i += 64) {
            int c = col[start + i];
            float4 ad = *(const float4*)(a_dst + (size_t)c * 4);
            float v0 = as4.x + ad.x, v1 = as4.y + ad.y, v2 = as4.z + ad.z, v3 = as4.w + ad.w;
            v0 = v0 > 0.f ? v0 : 0.2f * v0;  v1 = v1 > 0.f ? v1 : 0.2f * v1;
            v2 = v2 > 0.f ? v2 : 0.2f * v2;  v3 = v3 > 0.f ? v3 : 0.2f * v3;
            s0 += __expf(v0 - m0); s1 += __expf(v1 - m1);
            s2 += __expf(v2 - m2); s3 += __expf(v3 - m3);
        }
    }
    #pragma unroll
    for (int off = 1; off < 64; off <<= 1) {
        s0 += __shfl_xor(s0, off, 64);
        s1 += __shfl_xor(s1, off, 64);
        s2 += __shfl_xor(s2, off, 64);
        s3 += __shfl_xor(s3, off, 64);
    }

    __syncthreads();   // staged weights/cols visible to all lanes

    // Phase C: gather-accumulate; lane owns channels 2*lane, 2*lane+1
    const int h = lane >> 4;
    float sh = h == 0 ? s0 : h == 1 ? s1 : h == 2 ? s2 : s3;
    float mh = h == 0 ? m0 : h == 1 ? m1 : h == 2 ? m2 : m3;
    float ash = h == 0 ? as4.x : h == 1 ? as4.y : h == 2 ? as4.z : as4.w;
    const float inv = 1.0f / (sh + 1e-8f);
    float acc0 = 0.f, acc1 = 0.f;

    if (staged) {
        const float* wr = &lds_w[wid][0];
        const int*   cr = &lds_c[wid][0];
        int i = 0;
        for (; i + 3 < deg; i += 4) {
            int c0 = cr[i], c1 = cr[i + 1], c2 = cr[i + 2], c3 = cr[i + 3];
            float w0 = wr[i * 4 + h], w1 = wr[(i + 1) * 4 + h];
            float w2 = wr[(i + 2) * 4 + h], w3 = wr[(i + 3) * 4 + h];
            unsigned u0 = xp[(size_t)c0 * 64 + lane];
            unsigned u1 = xp[(size_t)c1 * 64 + lane];
            unsigned u2 = xp[(size_t)c2 * 64 + lane];
            unsigned u3 = xp[(size_t)c3 * 64 + lane];
            acc0 = fmaf(w0, __uint_as_float(u0 << 16), acc0);
            acc1 = fmaf(w0, __uint_as_float(u0 & 0xffff0000u), acc1);
            acc0 = fmaf(w1, __uint_as_float(u1 << 16), acc0);
            acc1 = fmaf(w1, __uint_as_float(u1 & 0xffff0000u), acc1);
            acc0 = fmaf(w2, __uint_as_float(u2 << 16), acc0);
            acc1 = fmaf(w2, __uint_as_float(u2 & 0xffff0000u), acc1);
            acc0 = fmaf(w3, __uint_as_float(u3 << 16), acc0);
            acc1 = fmaf(w3, __uint_as_float(u3 & 0xffff0000u), acc1);
        }
        for (; i < deg; ++i) {
            int c0 = cr[i];
            float w0 = wr[i * 4 + h];
            unsigned u0 = xp[(size_t)c0 * 64 + lane];
            acc0 = fmaf(w0, __uint_as_float(u0 << 16), acc0);
            acc1 = fmaf(w0, __uint_as_float(u0 & 0xffff0000u), acc1);
        }
    } else {
        for (int i = 0; i < deg; ++i) {
            int c = col[start + i];
            float ad = a_dst[(size_t)c * 4 + h];
            float v = ash + ad; v = v > 0.f ? v : 0.2f * v;
            float w = __expf(v - mh);
            unsigned u = xp[(size_t)c * 64 + lane];
            acc0 = fmaf(w, __uint_as_float(u << 16), acc0);
            acc1 = fmaf(w, __uint_as_float(u & 0xffff0000u), acc1);
        }
    }

    if (alive) {
        float2 bv = *(const float2*)(bias + 2 * lane);
        *(float2*)(out + (size_t)n * HC + 2 * lane) =
            make_float2(acc0 * inv + bv.x, acc1 * inv + bv.y);
    }
}

extern "C" void kernel_launch(void* const* d_in, const int* in_sizes, int n_in,
                              void* d_out, int out_size, void* d_ws, size_t ws_size,
                              hipStream_t stream) {
    const float* x       = (const float*)d_in[0];
    const float* weight  = (const float*)d_in[1];
    const float* att_src = (const float*)d_in[2];
    const float* att_dst = (const float*)d_in[3];
    const float* bias    = (const float*)d_in[4];
    const int*   row     = (const int*)d_in[5];
    const int*   col     = (const int*)d_in[6];
    float* out = (float*)d_out;

    const int n_nodes = in_sizes[0] / IN_C;   // 50000
    const int E = in_sizes[5];                // 1.6M

    char* ws = (char*)d_ws;
    unsigned* xp   = (unsigned*)ws;            ws += (size_t)n_nodes * 64 * sizeof(unsigned);
    float* a_src   = (float*)ws;               ws += (size_t)n_nodes * 4 * sizeof(float);
    float* a_dst   = (float*)ws;               ws += (size_t)n_nodes * 4 * sizeof(float);
    int*   row_ptr = (int*)ws;                 ws += (size_t)(n_nodes + 1) * sizeof(int);

    gemm_kernel<<<(n_nodes + GR - 1) / GR, 256, 0, stream>>>(x, weight, att_src, att_dst,
                                                             xp, a_src, a_dst, n_nodes);
    rowptr_kernel<<<(n_nodes + 256) / 256, 256, 0, stream>>>(row, row_ptr, n_nodes, E);
    agg_kernel<<<(n_nodes + 1) / 2, 128, 0, stream>>>(xp, a_src, a_dst, col, row_ptr,
                                                      bias, out, n_nodes);
}